// Round 13
// baseline (84.971 us; speedup 1.0000x reference)
//
#include <hip/hip_runtime.h>
#include <stdint.h>

// QuantConv1D (binary, K=3, Cin=128, Cout=256, VALID) + bias + BN(inference)
// via i8 MFMA: out[(b,t)][co] = dot * inv[co] + Cb[co],
// dot = sum_{tap,cin} sign(x[b,t+tap,cin]) * sign(ker[tap,cin,co]) (exact i32).
//
// R13: PERSISTENT blocks (turnover theory). 512 blocks x 512 thr (2/CU),
// each owns 4 consecutive t-windows of one batch:
//  - W-frags loaded ONCE per block (48 VGPR), reused for 4 tiles.
//  - LDS double-buffer: stage tile i+1 (global->reg early, pack->ds_write
//    late) while K-loop of tile i runs; ONE barrier per tile.
//  - acc stores issued AFTER the barrier -> drain overlaps next tile's
//    compute instead of serializing at block exit.
// Core K-loop / staging / store addressing identical to R12 (absmax 0.0).
// C/D layout (HW-verified m74/m101): col=lane&31, row=(reg&3)+8*(reg>>2)+4*(lane>>5).

#define B 64
#define T 2048
#define CIN 128
#define COUT 256
#define KW 3
#define TOUT (T - KW + 1)        // 2046
#define MROWS 64                 // output t-rows per tile
#define AROWS (MROWS + KW - 1)   // 66 staged x-rows
#define NSTG (AROWS * 32)        // 2112 staged dwords
#define NWI 32                   // t-windows per batch (last overlaps: t0=1982)
#define TPB 4                    // tiles per block
#define NBLK (B * NWI / TPB)     // 512 blocks

typedef int i32x4  __attribute__((ext_vector_type(4)));
typedef int i32x16 __attribute__((ext_vector_type(16)));

// ---- pack kernel signs (i8 +1/-1, co-major) + fold BN affine ----
// kb8[co*384 + tap*128 + cin]
__global__ __launch_bounds__(256) void pack_w_kernel(const float* __restrict__ ker,
                                                     const float* __restrict__ bias,
                                                     const float* __restrict__ beta,
                                                     const float* __restrict__ mean,
                                                     const float* __restrict__ var,
                                                     uint8_t* __restrict__ kb8,
                                                     float* __restrict__ Ainv,
                                                     float* __restrict__ Cb) {
    const int tap = blockIdx.x >> 2;    // 0..2
    const int q   = blockIdx.x & 3;     // cin quarter
    const int co  = threadIdx.x;        // 0..255
    #pragma unroll
    for (int j = 0; j < 8; ++j) {
        int cin0 = q * 32 + j * 4;
        const float* s = ker + ((size_t)(tap * CIN + cin0)) * COUT + co;
        uint32_t w = (s[0]                >= 0.f ? 0x01u : 0xFFu)
                   | ((s[(size_t)COUT]     >= 0.f ? 0x01u : 0xFFu) << 8)
                   | ((s[(size_t)2 * COUT] >= 0.f ? 0x01u : 0xFFu) << 16)
                   | ((s[(size_t)3 * COUT] >= 0.f ? 0x01u : 0xFFu) << 24);
        *(uint32_t*)(kb8 + (size_t)co * 384 + tap * 128 + cin0) = w;
    }
    if (blockIdx.x == 0) {
        float inv = 1.0f / sqrtf(var[co] + 1e-3f);
        Ainv[co] = inv;
        Cb[co]   = (bias[co] - mean[co]) * inv + beta[co];
    }
}

__device__ __forceinline__ int t0_of(int wi) {
    return (wi == NWI - 1) ? (TOUT - MROWS) : wi * MROWS;   // 1982 last
}

// ---- persistent fused stage + MFMA conv ----
__global__ __launch_bounds__(512, 4) void conv_mfma_persist(const float* __restrict__ x,
                                                            const uint8_t* __restrict__ kb8,
                                                            const float* __restrict__ Ainv,
                                                            const float* __restrict__ Cb,
                                                            float* __restrict__ out) {
    const int tid  = threadIdx.x;
    const int l    = tid & 63;
    const int h    = l >> 5;             // k-half / t-row offset selector
    const int ln   = l & 31;
    const int wv   = tid >> 6;           // 0..7: cout tile wv*32..+31
    const int bb   = blockIdx.x >> 3;    // batch
    const int wseg = blockIdx.x & 7;     // group of TPB consecutive windows

    __shared__ uint32_t As[2][NSTG];     // double-buffered staged sign-i8

    // --- W-frags once per block: lane = col, k-half h ---
    const int col = (wv << 5) + ln;
    i32x4 Bf[12];
    {
        const uint8_t* bp = kb8 + (size_t)col * 384 + h * 16;
        #pragma unroll
        for (int a = 0; a < 12; ++a)
            Bf[a] = *(const i32x4*)(bp + a * 32);
    }
    const float ainv = Ainv[col];
    const float cb   = Cb[col];

    const float* xbase = x + (size_t)bb * T * CIN;
    float4 f[5];

    // stage phase A: issue global loads for window at t0 into regs
    auto stage_load = [&](int t0) {
        const float* xb = xbase + (size_t)t0 * CIN;
        #pragma unroll
        for (int s5 = 0; s5 < 5; ++s5) {
            int idx = tid + s5 * 512;
            if (s5 < 4 || idx < NSTG)
                f[s5] = *(const float4*)(xb + (size_t)(idx >> 5) * CIN + (idx & 31) * 4);
        }
    };
    // stage phase B: pack signs + swizzled ds_write
    auto stage_write = [&](uint32_t* dst) {
        #pragma unroll
        for (int s5 = 0; s5 < 5; ++s5) {
            int idx = tid + s5 * 512;
            if (s5 < 4 || idx < NSTG) {
                float4 v = f[s5];
                uint32_t w = (v.x >= 0.f ? 0x01u : 0xFFu)
                           | ((v.y >= 0.f ? 0x01u : 0xFFu) << 8)
                           | ((v.z >= 0.f ? 0x01u : 0xFFu) << 16)
                           | ((v.w >= 0.f ? 0x01u : 0xFFu) << 24);
                int row = idx >> 5, c4 = idx & 31;
                int slot = (c4 >> 2) ^ (row & 7);        // 16B-slot swizzle
                dst[row * 32 + slot * 4 + (c4 & 3)] = w;
            }
        }
    };

    // --- prologue: stage tile 0 ---
    stage_load(t0_of(wseg * TPB));
    stage_write(As[0]);
    __syncthreads();

    for (int it = 0; it < TPB; ++it) {
        const int wi = wseg * TPB + it;
        const int t0 = t0_of(wi);

        // issue next tile's loads early (hide under K-loop)
        if (it + 1 < TPB) stage_load(t0_of(wi + 1));

        // --- K-loop: 3 taps x 4 K32-steps x 2 t-tiles = 24 MFMA ---
        i32x16 acc0 = {}, acc1 = {};
        const char* Ab = (const char*)As[it & 1];
        #pragma unroll
        for (int tap = 0; tap < KW; ++tap) {
            #pragma unroll
            for (int s = 0; s < 4; ++s) {
                const int slot = s * 2 + h;
                const i32x4 bf = Bf[tap * 4 + s];
                const int r0 = ln + tap;
                i32x4 A0 = *(const i32x4*)(Ab + r0 * 128 + ((slot ^ (r0 & 7)) << 4));
                acc0 = __builtin_amdgcn_mfma_i32_32x32x32_i8(A0, bf, acc0, 0, 0, 0);
                const int r1 = r0 + 32;
                i32x4 A1 = *(const i32x4*)(Ab + r1 * 128 + ((slot ^ (r1 & 7)) << 4));
                acc1 = __builtin_amdgcn_mfma_i32_32x32x32_i8(A1, bf, acc1, 0, 0, 0);
            }
        }

        // pack + write next tile into the other LDS buffer
        if (it + 1 < TPB) stage_write(As[(it + 1) & 1]);
        __syncthreads();

        // --- store tile it AFTER the barrier: drain overlaps next tile ---
        float* ob = out + ((size_t)bb * TOUT + t0) * COUT + col;
        #pragma unroll
        for (int reg = 0; reg < 16; ++reg) {
            const int trow = (reg & 3) + 8 * (reg >> 2) + 4 * h;
            ob[(size_t)trow * COUT]        = fmaf((float)acc0[reg], ainv, cb);
            ob[(size_t)(32 + trow) * COUT] = fmaf((float)acc1[reg], ainv, cb);
        }
    }
}

extern "C" void kernel_launch(void* const* d_in, const int* in_sizes, int n_in,
                              void* d_out, int out_size, void* d_ws, size_t ws_size,
                              hipStream_t stream) {
    const float* x    = (const float*)d_in[0];
    const float* ker  = (const float*)d_in[1];
    const float* bias = (const float*)d_in[2];
    const float* beta = (const float*)d_in[3];
    const float* mean = (const float*)d_in[4];
    const float* var  = (const float*)d_in[5];
    float* out = (float*)d_out;

    // workspace: kb8 (96 KB) | Ainv (1 KB) | Cb (1 KB)
    uint8_t* kb8  = (uint8_t*)d_ws;
    float*   Ainv = (float*)(kb8 + (size_t)COUT * 384);
    float*   Cb   = Ainv + COUT;

    pack_w_kernel<<<KW * 4, 256, 0, stream>>>(ker, bias, beta, mean, var, kb8, Ainv, Cb);
    conv_mfma_persist<<<NBLK, 512, 0, stream>>>(x, kb8, Ainv, Cb, out);
}

// Round 14
// 52.812 us; speedup vs baseline: 1.6089x; 1.6089x over previous
//
#include <hip/hip_runtime.h>
#include <stdint.h>

// QuantConv1D (binary, K=3, Cin=128, Cout=256, VALID) + bias + BN(inference)
// via XNOR-popcount on bit-packed signs.
//
// R14: store/load DECOUPLING. vmcnt is an in-order counter shared by loads
// and stores; any wait for a load forces completion of all prior stores.
// Every fused variant (R4-R8) interleaved loads+stores per body, injecting
// HBM store-drain into the VALU dependency chain. Fix: conv waves load
// EVERYTHING in the prologue (12 kj + 10 window rows + affine), then run a
// pure VALU+store loop -- vmcnt counts only stores, never waited on.
//  - pack_x: 67MB read -> 2MB packed bits (R8's, measured ~11us).
//  - conv: wave = 8 outputs x 256 couts; 1KB contiguous NT store per t.
// Bit order: word i bit b <-> cin = 4b+i (ballot/float4-lane order), same
// permutation in kbT; popcount is permutation-invariant.

#define B 64
#define T 2048
#define CIN 128
#define COUT 256
#define KW 3
#define TOUT (T - KW + 1)   // 2046
#define WPB 4               // waves per block
#define PACK_ROWS 32        // rows packed per wave in pack_x
#define TW2 8               // outputs per conv wave
#define NW2 256             // windows per batch (last overlaps: t0=2038)

typedef float f32x4 __attribute__((ext_vector_type(4)));

// ---- pack kernel signs, transposed co-major layout ----
// kbT[co*12 + tap*4 + i], word i bit b <-> cin = 4b+i
__global__ __launch_bounds__(256) void pack_w_kernel(const float* __restrict__ ker,
                                                     const float* __restrict__ bias,
                                                     const float* __restrict__ beta,
                                                     const float* __restrict__ mean,
                                                     const float* __restrict__ var,
                                                     uint32_t* __restrict__ kbT,
                                                     float* __restrict__ A,
                                                     float* __restrict__ C) {
    int k  = blockIdx.x >> 2;       // 0..2
    int i  = blockIdx.x & 3;        // word index 0..3
    int co = threadIdx.x;           // 0..255
    const float* src = ker + ((size_t)(k * CIN + i)) * COUT + co;
    uint32_t wbits = 0;
    #pragma unroll 8
    for (int bb = 0; bb < 32; ++bb) {
        if (src[(size_t)(4 * bb) * COUT] >= 0.0f) wbits |= (1u << bb);
    }
    kbT[(size_t)co * 12 + k * 4 + i] = wbits;
    if (blockIdx.x == 0) {
        float inv = 1.0f / sqrtf(var[co] + 1e-3f);
        A[co] = -2.0f * inv;
        C[co] = (384.0f + bias[co] - mean[co]) * inv + beta[co];
    }
}

// ---- pass 1: pack x signs -> xb[row] = uint4 (128 bits, permuted order) ----
__global__ __launch_bounds__(256) void pack_x_kernel(const float* __restrict__ x,
                                                     uint4* __restrict__ xb) {
    const int l   = threadIdx.x & 63;
    const int wid = blockIdx.x * WPB + (threadIdx.x >> 6);   // 0..4095
    const size_t row0 = (size_t)wid * PACK_ROWS;
    const float* p = x + row0 * CIN + l * 4;
    uint4* q = xb + row0;

    #pragma unroll 4
    for (int i = 0; i < PACK_ROWS / 2; ++i) {
        float4 v = *(const float4*)(p + (size_t)i * 2 * CIN);
        uint64_t m0 = __ballot(v.x >= 0.0f);
        uint64_t m1 = __ballot(v.y >= 0.0f);
        uint64_t m2 = __ballot(v.z >= 0.0f);
        uint64_t m3 = __ballot(v.w >= 0.0f);
        if (l == 0) {
            q[2 * i] = make_uint4((uint32_t)m0, (uint32_t)m1,
                                  (uint32_t)m2, (uint32_t)m3);
        } else if (l == 1) {
            q[2 * i + 1] = make_uint4((uint32_t)(m0 >> 32), (uint32_t)(m1 >> 32),
                                      (uint32_t)(m2 >> 32), (uint32_t)(m3 >> 32));
        }
    }
}

// ---- pass 2: conv, loads ONLY in prologue, then pure VALU + NT stores ----
__global__ __launch_bounds__(256) void conv_kernel(const uint4* __restrict__ xb,
                                                   const uint32_t* __restrict__ kbT,
                                                   const float* __restrict__ A,
                                                   const float* __restrict__ C,
                                                   float* __restrict__ out) {
    const int l   = threadIdx.x & 63;
    const int wv  = threadIdx.x >> 6;
    const int gw  = blockIdx.x * WPB + wv;          // 0..B*NW2-1
    const int b   = gw >> 8;                        // /NW2
    const int win = gw & (NW2 - 1);
    const int t0  = (win < NW2 - 1) ? win * TW2 : (TOUT - TW2);  // 2038 last

    // per-thread kernel bits: kj[j][tap] for cout co0+j (192B contiguous)
    const int co0 = l * 4;
    uint4 kj[4][KW];
    #pragma unroll
    for (int j = 0; j < 4; ++j)
        #pragma unroll
        for (int k = 0; k < KW; ++k)
            kj[j][k] = *(const uint4*)(kbT + (size_t)(co0 + j) * 12 + k * 4);
    const float4 av = *(const float4*)(A + co0);
    const float4 cv = *(const float4*)(C + co0);

    // window rows: wave-uniform contiguous 160B, loaded BEFORE any store
    const uint4* xr = xb + (size_t)b * T + t0;
    uint4 R[TW2 + 2];
    #pragma unroll
    for (int r = 0; r < TW2 + 2; ++r) R[r] = xr[r];

    float* orow = out + ((size_t)b * TOUT + t0) * COUT + co0;
    #pragma unroll
    for (int t = 0; t < TW2; ++t) {
        f32x4 o;
        #pragma unroll
        for (int j = 0; j < 4; ++j) {
            int s = 0;
            #pragma unroll
            for (int tap = 0; tap < KW; ++tap) {
                const uint4 r = R[t + tap];
                const uint4 k = kj[j][tap];
                s += __popc(r.x ^ k.x) + __popc(r.y ^ k.y)
                   + __popc(r.z ^ k.z) + __popc(r.w ^ k.w);
            }
            o[j] = fmaf((float)s, (&av.x)[j], (&cv.x)[j]);
        }
        __builtin_nontemporal_store(o, (f32x4*)(orow + (size_t)t * COUT));
    }
}

extern "C" void kernel_launch(void* const* d_in, const int* in_sizes, int n_in,
                              void* d_out, int out_size, void* d_ws, size_t ws_size,
                              hipStream_t stream) {
    const float* x    = (const float*)d_in[0];
    const float* ker  = (const float*)d_in[1];
    const float* bias = (const float*)d_in[2];
    const float* beta = (const float*)d_in[3];
    const float* mean = (const float*)d_in[4];
    const float* var  = (const float*)d_in[5];
    float* out = (float*)d_out;

    // workspace: kbT (12 KB) | A (1 KB) | C (1 KB) | xbits (2 MB)
    uint32_t* kbT = (uint32_t*)d_ws;
    float*    A   = (float*)(kbT + (size_t)COUT * 12);
    float*    C   = A + COUT;
    uint4*    xb  = (uint4*)(C + COUT);

    pack_x_kernel<<<(B * T / PACK_ROWS) / WPB, 256, 0, stream>>>(x, xb);
    pack_w_kernel<<<KW * 4, 256, 0, stream>>>(ker, bias, beta, mean, var, kbT, A, C);
    conv_kernel<<<(B * NW2) / WPB, 256, 0, stream>>>(xb, kbT, A, C, out);
}